// Round 11
// baseline (143.683 us; speedup 1.0000x reference)
//
#include <hip/hip_runtime.h>
#include <hip/hip_bf16.h>
#include <stdint.h>

// Problem constants
#define TSEQ   2048
#define DMODEL 1024
#define NHEAD  16
#define HDIM   64

typedef __attribute__((ext_vector_type(8))) __bf16 bf16x8;
typedef __attribute__((ext_vector_type(4))) float f32x4;
typedef __attribute__((ext_vector_type(8))) unsigned short u16x8;

// log2(e)/8 : folds the 1/sqrt(64) logit scale into exp2 (applied to Q in gemm1)
#define SC_LOG2E 0.18033688011112042f

#if __has_builtin(__builtin_amdgcn_exp2f)
#define EXP2F(x) __builtin_amdgcn_exp2f(x)
#else
#define EXP2F(x) __expf(0.6931471805599453f * (x))
#endif

__device__ __forceinline__ unsigned short f2bf(float f) {
    __hip_bfloat16 h = __float2bfloat16(f);
    return __builtin_bit_cast(unsigned short, h);
}
__device__ __forceinline__ float bf2f(unsigned short u) {
    union { unsigned int i; float f; } v;
    v.i = ((unsigned int)u) << 16;
    return v.f;
}
__device__ __forceinline__ unsigned int cvtpk_bf16(float lo, float hi) {
    unsigned int r;
    asm("v_cvt_pk_bf16_f32 %0, %1, %2" : "=v"(r) : "v"(lo), "v"(hi));
    return r;
}

__device__ __forceinline__ void gld_lds16(const void* g, void* s) {
    __builtin_amdgcn_global_load_lds(
        (__attribute__((address_space(1))) void*)(void*)g,
        (__attribute__((address_space(3))) void*)s, 16, 0, 0);
}

// ---------------------------------------------------------------------------
// fused fp32 -> bf16 cast for x, w_in, w_out (one launch)
// ---------------------------------------------------------------------------
#define NX4  (4096 * 1024 / 4)
#define NWI4 (3072 * 1024 / 4)
#define NWO4 (1024 * 1024 / 4)
__global__ void cast3_kernel(const float* __restrict__ x,
                             const float* __restrict__ wi,
                             const float* __restrict__ wo,
                             unsigned short* __restrict__ ox,
                             unsigned short* __restrict__ owi,
                             unsigned short* __restrict__ owo) {
    int i = blockIdx.x * blockDim.x + threadIdx.x;
    const float* s;
    unsigned short* d;
    int off;
    if (i < NX4)              { s = x;  d = ox;  off = i; }
    else if (i < NX4 + NWI4)  { s = wi; d = owi; off = i - NX4; }
    else                      { s = wo; d = owo; off = i - NX4 - NWI4; }
    float4 v = ((const float4*)s)[off];
    ushort4 u;
    u.x = f2bf(v.x); u.y = f2bf(v.y); u.z = f2bf(v.z); u.w = f2bf(v.w);
    ((ushort4*)d)[off] = u;
}

// ---------------------------------------------------------------------------
// GEMM: C[m,n] = sum_k A[m,k] * B[n,k]   (A:[M,K] bf16, B:[N,K] bf16)
// For STORE_F32==false (the QKV GEMM), Q columns (bn<8, col<1024) are
// pre-scaled by SC_LOG2E so attention's exp2 needs no per-element scale.
// ---------------------------------------------------------------------------
template<bool STORE_F32>
__global__ __launch_bounds__(256, 3)
void gemm_bt(const unsigned short* __restrict__ A,
             const unsigned short* __restrict__ B,
             void* __restrict__ C, int M, int N, int K) {
    (void)M;
    __shared__ unsigned short As[128 * 32];
    __shared__ unsigned short Bs[128 * 32];
    const int tid = threadIdx.x;
    const int nb = N >> 7;
    const int bm = blockIdx.x / nb;
    const int bn = blockIdx.x % nb;
    const int w  = tid >> 6, l = tid & 63;
    const int wr = w >> 1,  wc = w & 1;
    const int lr = l & 15,  lg = l >> 4;

    f32x4 acc[4][4] = {};

    const unsigned short* Ab = A + (size_t)bm * 128 * K;
    const unsigned short* Bb = B + (size_t)bn * 128 * K;

    const int c0 = tid, c1 = tid + 256;
    const int ar0 = c0 >> 2, ak0 = (c0 & 3) * 8;
    const int ar1 = c1 >> 2, ak1 = (c1 & 3) * 8;

    for (int kt = 0; kt < K; kt += 32) {
        __syncthreads();
        gld_lds16(Ab + (size_t)ar0 * K + kt + ak0, As + c0 * 8);
        gld_lds16(Ab + (size_t)ar1 * K + kt + ak1, As + c1 * 8);
        gld_lds16(Bb + (size_t)ar0 * K + kt + ak0, Bs + c0 * 8);
        gld_lds16(Bb + (size_t)ar1 * K + kt + ak1, Bs + c1 * 8);
        __syncthreads();

        bf16x8 af[4], bfr[4];
#pragma unroll
        for (int i = 0; i < 4; i++)
            af[i] = *(const bf16x8*)(As + (wr * 64 + i * 16 + lr) * 32 + lg * 8);
#pragma unroll
        for (int i = 0; i < 4; i++)
            bfr[i] = *(const bf16x8*)(Bs + (wc * 64 + i * 16 + lr) * 32 + lg * 8);
#pragma unroll
        for (int mi = 0; mi < 4; mi++)
#pragma unroll
            for (int ni = 0; ni < 4; ni++)
                acc[mi][ni] = __builtin_amdgcn_mfma_f32_16x16x32_bf16(
                    af[mi], bfr[ni], acc[mi][ni], 0, 0, 0);
    }

    const int row0 = bm * 128 + wr * 64;
    const int col0 = bn * 128 + wc * 64;
    const float qsc = (!STORE_F32 && bn < 8) ? SC_LOG2E : 1.0f;
#pragma unroll
    for (int mi = 0; mi < 4; mi++)
#pragma unroll
        for (int ni = 0; ni < 4; ni++)
#pragma unroll
            for (int r = 0; r < 4; r++) {
                const int row = row0 + mi * 16 + lg * 4 + r;
                const int col = col0 + ni * 16 + lr;
                if (STORE_F32)
                    ((float*)C)[(size_t)row * N + col] = acc[mi][ni][r];
                else
                    ((unsigned short*)C)[(size_t)row * N + col] =
                        f2bf(acc[mi][ni][r] * qsc);
            }
}

// ---------------------------------------------------------------------------
// V transpose + per-tile column sums:
//   VTg[bh][d][k] = V[b][k][h*64+d]
//   ts[bh][t][d]  = sum_{k in tile t} V[k][d]
// ---------------------------------------------------------------------------
__global__ __launch_bounds__(256)
void vtran_kernel(const unsigned short* __restrict__ qkv,
                  unsigned short* __restrict__ vtg,
                  float* __restrict__ ts) {
    __shared__ unsigned short T[64][72];
    const int bid = blockIdx.x;
    const int kb_ = bid & 31;
    const int bh  = bid >> 5;
    const int b = bh >> 4, h = bh & 15;
    const int tid = threadIdx.x;

    const int r = tid >> 2, cq = (tid & 3) * 16;
    const unsigned short* src =
        qkv + ((size_t)(b * TSEQ + kb_ * 64 + r)) * 3072 + 2048 + h * 64 + cq;
    u16x8 v0 = *(const u16x8*)src;
    u16x8 v1 = *(const u16x8*)(src + 8);
#pragma unroll
    for (int i = 0; i < 8; i++) T[r][cq + i] = v0[i];
#pragma unroll
    for (int i = 0; i < 8; i++) T[r][cq + 8 + i] = v1[i];
    __syncthreads();

    const int d = tid >> 2, kq = (tid & 3) * 16;
    u16x8 o0, o1;
#pragma unroll
    for (int i = 0; i < 8; i++) o0[i] = T[kq + i][d];
#pragma unroll
    for (int i = 0; i < 8; i++) o1[i] = T[kq + 8 + i][d];
    unsigned short* dst = vtg + ((size_t)bh * 64 + d) * TSEQ + kb_ * 64 + kq;
    *(u16x8*)dst = o0;
    *(u16x8*)(dst + 8) = o1;

    // per-tile V column sums (thread holds V[kq..kq+15][d])
    float ps = 0.f;
#pragma unroll
    for (int i = 0; i < 8; i++) ps += bf2f(o0[i]) + bf2f(o1[i]);
    ps += __shfl_xor(ps, 1);
    ps += __shfl_xor(ps, 2);
    if ((tid & 3) == 0)
        ts[((size_t)bh * 32 + kb_) * 64 + d] = ps;
}

// ---------------------------------------------------------------------------
// Attention v11: k-parity split for uniform block duration + backfill.
// Block = (bh, strip-pair (2s,2s+1), parity); processes k-tiles
// kt = parity + 2t, t = 0..s (s+1 staged tiles for EVERY block -> per-pair
// duration halves; 1024 blocks -> ~3 resident/CU + backfill; s=15 first).
// Partial o (f32) and rsum accumulate via atomicAdd into zeroed buffers —
// exactly 2 adds per address, IEEE-commutative -> bit-deterministic.
// Diagonal tile falls in the parity block owning kt==lastkt automatically.
// tpv (tsuf closed form) + nmask added by the parity-0 block only.
// ---------------------------------------------------------------------------
__global__ __launch_bounds__(256, 3)
void attn_kernel(const unsigned short* __restrict__ qkv,
                 const unsigned short* __restrict__ vtg,
                 const float* __restrict__ ts,
                 float* __restrict__ o_accum,
                 float* __restrict__ rsum) {
    __shared__ __attribute__((aligned(16))) unsigned short Ks[2][4096];
    __shared__ __attribute__((aligned(16))) unsigned short Vs[2][4096];
    __shared__ __attribute__((aligned(16))) unsigned short Pl[4][32 * 72];

    const int tid = threadIdx.x;
    const int w = tid >> 6, l = tid & 63, lr = l & 15, lg = l >> 4;
    const int bid = blockIdx.x;
    const int jj = bid >> 5;
    const int pairidx = jj >> 1;                     // 0..15
    const int parity  = jj & 1;
    const int s  = 15 - pairidx;                     // heavy pairs first
    const int bh = (bid & 7) * 4 + ((bid >> 3) & 3); // XCD-pinned (b,h)
    const int b = bh >> 4, h = bh & 15;
    const int strip  = 2 * s + ((w < 2) ? 1 : 0);    // this wave's 64-row strip
    const int lastkt = strip;
    const int ntl = s + 1;                           // local tiles kt=parity+2t
    const size_t rowbase = (size_t)b * TSEQ;
    const int qrow0 = strip * 64 + (w & 1) * 32;

    // Q fragments, pre-scaled by SC_LOG2E in gemm1
    bf16x8 qf[2][2];
#pragma unroll
    for (int mi = 0; mi < 2; mi++) {
        const unsigned short* qp =
            qkv + (rowbase + qrow0 + mi * 16 + lr) * 3072 + h * 64 + lg * 8;
        qf[mi][0] = *(const bf16x8*)qp;
        qf[mi][1] = *(const bf16x8*)(qp + 32);
    }

    // staging source pointers, fragment order
    const unsigned short* ksrc[2];
    const unsigned short* vsrc[2];
#pragma unroll
    for (int jx = 0; jx < 2; jx++) {
        const int d = tid + jx * 256;
        const int fr = (d >> 7) * 16 + (d & 15);
        const int cc = ((d >> 6) & 1) * 32 + ((d & 63) >> 4) * 8;
        ksrc[jx] = qkv + (rowbase + fr) * 3072 + 1024 + h * 64 + cc;
        vsrc[jx] = vtg + ((size_t)bh * 64 + fr) * TSEQ + cc;
    }

#define STAGE(kt_, bufi) do {                                      \
        const size_t ko_ = (size_t)(kt_) * 64 * 3072;              \
        const int vo_ = (kt_) * 64;                                \
        gld_lds16(ksrc[0] + ko_, &Ks[bufi][tid * 8]);              \
        gld_lds16(ksrc[1] + ko_, &Ks[bufi][tid * 8 + 2048]);       \
        gld_lds16(vsrc[0] + vo_, &Vs[bufi][tid * 8]);              \
        gld_lds16(vsrc[1] + vo_, &Vs[bufi][tid * 8 + 2048]);       \
    } while (0)

    f32x4 o[2][4] = {};
    float ps[2] = {0.f, 0.f};     // lane-local rsum partial for q = (mi, lr)
    unsigned short* pw = &Pl[w][0];

    STAGE(parity, 0);
    __syncthreads();

    for (int t = 0; t < ntl; ++t) {
        const int kt = parity + 2 * t;
        if (t + 1 < ntl) STAGE(parity + 2 * (t + 1), (t + 1) & 1);

        if (kt <= lastkt) {   // wave-uniform skip past this strip's diag
            const unsigned short* kc = Ks[t & 1];
            const unsigned short* vc = Vs[t & 1];

            bf16x8 kb[4][2];
#pragma unroll
            for (int f = 0; f < 4; f++) {
                kb[f][0] = *(const bf16x8*)(kc + ((f * 2 + 0) * 64 + l) * 8);
                kb[f][1] = *(const bf16x8*)(kc + ((f * 2 + 1) * 64 + l) * 8);
            }

            // S^T = K Q^T (swapped operands): lane holds q=lr, k=f*16+lg*4+r
            float pvv[2][4][4];
            __builtin_amdgcn_s_setprio(1);
#pragma unroll
            for (int mi = 0; mi < 2; mi++)
#pragma unroll
                for (int f = 0; f < 4; f++) {
                    f32x4 z = {0.f, 0.f, 0.f, 0.f};
                    f32x4 sv = __builtin_amdgcn_mfma_f32_16x16x32_bf16(kb[f][0], qf[mi][0], z, 0, 0, 0);
                    sv = __builtin_amdgcn_mfma_f32_16x16x32_bf16(kb[f][1], qf[mi][1], sv, 0, 0, 0);
#pragma unroll
                    for (int r = 0; r < 4; r++) pvv[mi][f][r] = sv[r];
                }
            __builtin_amdgcn_s_setprio(0);

            if (kt == lastkt) {  // diagonal tile only: tril zeroing (exp2(0)=1)
#pragma unroll
                for (int mi = 0; mi < 2; mi++) {
                    const int qr = qrow0 + mi * 16 + lr;
#pragma unroll
                    for (int f = 0; f < 4; f++)
#pragma unroll
                        for (int r = 0; r < 4; r++) {
                            const int kcol = kt * 64 + f * 16 + lg * 4 + r;
                            if (kcol > qr) pvv[mi][f][r] = 0.f;
                        }
                }
            }

            // exp2 + lane-local rsum + cvt_pk + b64 pack to P tile
#pragma unroll
            for (int mi = 0; mi < 2; mi++)
#pragma unroll
                for (int f = 0; f < 4; f++) {
                    float p0 = EXP2F(pvv[mi][f][0]);
                    float p1 = EXP2F(pvv[mi][f][1]);
                    float p2 = EXP2F(pvv[mi][f][2]);
                    float p3 = EXP2F(pvv[mi][f][3]);
                    ps[mi] += (p0 + p1) + (p2 + p3);
                    uint2 pk;
                    pk.x = cvtpk_bf16(p0, p1);
                    pk.y = cvtpk_bf16(p2, p3);
                    *(uint2*)(pw + (mi * 16 + lr) * 72 + f * 16 + lg * 4) = pk;
                }

            bf16x8 pa[2][2];
#pragma unroll
            for (int mi = 0; mi < 2; mi++) {
                pa[mi][0] = *(const bf16x8*)(pw + (mi * 16 + lr) * 72 + lg * 8);
                pa[mi][1] = *(const bf16x8*)(pw + (mi * 16 + lr) * 72 + 32 + lg * 8);
            }
            bf16x8 vb[4][2];
#pragma unroll
            for (int f2 = 0; f2 < 4; f2++) {
                vb[f2][0] = *(const bf16x8*)(vc + ((f2 * 2 + 0) * 64 + l) * 8);
                vb[f2][1] = *(const bf16x8*)(vc + ((f2 * 2 + 1) * 64 + l) * 8);
            }
            __builtin_amdgcn_s_setprio(1);
#pragma unroll
            for (int mi = 0; mi < 2; mi++)
#pragma unroll
                for (int f2 = 0; f2 < 4; f2++) {
                    o[mi][f2] = __builtin_amdgcn_mfma_f32_16x16x32_bf16(pa[mi][0], vb[f2][0], o[mi][f2], 0, 0, 0);
                    o[mi][f2] = __builtin_amdgcn_mfma_f32_16x16x32_bf16(pa[mi][1], vb[f2][1], o[mi][f2], 0, 0, 0);
                }
            __builtin_amdgcn_s_setprio(0);
        }

        __syncthreads();
    }
#undef STAGE

    // rsum finalize: reduce across lg groups (lanes sharing lr)
#pragma unroll
    for (int mi = 0; mi < 2; mi++) {
        ps[mi] += __shfl_xor(ps[mi], 16);
        ps[mi] += __shfl_xor(ps[mi], 32);
    }
    const float nmask = (parity == 0) ? (float)((31 - lastkt) * 64) : 0.f;
    if (lg == 0) {
#pragma unroll
        for (int mi = 0; mi < 2; mi++)
            atomicAdd(&rsum[(rowbase + qrow0 + mi * 16 + lr) * 16 + h],
                      ps[mi] + nmask);
    }

    // future-tile V column sums: parity-0 block contributes them (once/row)
    float tpv[4] = {0.f, 0.f, 0.f, 0.f};
    if (parity == 0) {
        for (int t = lastkt + 1; t < 32; ++t) {
            const float* tsp = ts + ((size_t)bh * 32 + t) * 64 + lr;
#pragma unroll
            for (int f2 = 0; f2 < 4; f2++) tpv[f2] += tsp[f2 * 16];
        }
    }

    // partial numerator accumulate (2 atomic adds per address total)
#pragma unroll
    for (int mi = 0; mi < 2; mi++)
#pragma unroll
        for (int r = 0; r < 4; r++) {
            const size_t row = rowbase + qrow0 + mi * 16 + lg * 4 + r;
#pragma unroll
            for (int f2 = 0; f2 < 4; f2++)
                atomicAdd(&o_accum[row * 1024 + h * 64 + f2 * 16 + lr],
                          o[mi][f2][r] + tpv[f2]);
        }
}

// ---------------------------------------------------------------------------
// Normalize: ao = bf16(o_accum / rsum)   (4096x1024, float4 per thread)
// ---------------------------------------------------------------------------
__global__ __launch_bounds__(256)
void norm_kernel(const float* __restrict__ o_accum,
                 const float* __restrict__ rsum,
                 unsigned short* __restrict__ ao) {
    const int i = blockIdx.x * 256 + threadIdx.x;   // float4 index, 1048576
    float4 v = ((const float4*)o_accum)[i];
    const int row = i >> 8;
    const int h = (i & 255) >> 4;
    const float inv = 1.f / rsum[row * 16 + h];
    ushort4 u;
    u.x = f2bf(v.x * inv); u.y = f2bf(v.y * inv);
    u.z = f2bf(v.z * inv); u.w = f2bf(v.w * inv);
    ((ushort4*)ao)[i] = u;
}

// ---------------------------------------------------------------------------
extern "C" void kernel_launch(void* const* d_in, const int* in_sizes, int n_in,
                              void* d_out, int out_size, void* d_ws, size_t ws_size,
                              hipStream_t stream) {
    const float* x     = (const float*)d_in[0];
    const float* w_in  = (const float*)d_in[1];
    const float* w_out = (const float*)d_in[2];

    // Layout (ushort offsets). o_accum (f32, 16.78MB) reuses xb+wib+spare;
    // qkv/ao/ts/vtg unchanged; wob moved to tail; rsum after it.
    unsigned short* ws  = (unsigned short*)d_ws;
    unsigned short* xb  = ws;                              // 4096*1024
    unsigned short* wib = ws + (size_t)4194304;            // 3072*1024
    float* o_accum      = (float*)ws;                      // [4096][1024] f32
    unsigned short* qkv = ws + (size_t)8388608;            // 4096*3072
    unsigned short* ao  = ws + (size_t)20971520;           // 4096*1024
    float* tsbuf        = (float*)(ws + (size_t)25165824); // 32*32*64 f32
    unsigned short* vtg = ws + (size_t)25296896;           // 32*64*2048
    unsigned short* wob = ws + (size_t)29491200;           // 1024*1024 (tail)
    float* rsum         = (float*)(ws + (size_t)30539776); // 4096*16 f32

    cast3_kernel<<<(NX4 + NWI4 + NWO4) / 256, 256, 0, stream>>>(
        x, w_in, w_out, xb, wib, wob);

    gemm_bt<false><<<(4096 / 128) * (3072 / 128), 256, 0, stream>>>(
        xb, wib, qkv, 4096, 3072, 1024);
    vtran_kernel<<<32 * 32, 256, 0, stream>>>(qkv, vtg, tsbuf);

    hipMemsetAsync(o_accum, 0, (size_t)4096 * 1024 * 4, stream);
    hipMemsetAsync(rsum, 0, (size_t)4096 * 16 * 4, stream);

    attn_kernel<<<1024, 256, 0, stream>>>(qkv, vtg, tsbuf, o_accum, rsum);
    norm_kernel<<<4096, 256, 0, stream>>>(o_accum, rsum, ao);

    gemm_bt<true><<<(4096 / 128) * (1024 / 128), 256, 0, stream>>>(
        ao, wob, (float*)d_out, 4096, 1024, 1024);
}

// Round 12
// 108.668 us; speedup vs baseline: 1.3222x; 1.3222x over previous
//
#include <hip/hip_runtime.h>
#include <hip/hip_bf16.h>
#include <stdint.h>

// Problem constants
#define TSEQ   2048
#define DMODEL 1024
#define NHEAD  16
#define HDIM   64

typedef __attribute__((ext_vector_type(8))) __bf16 bf16x8;
typedef __attribute__((ext_vector_type(4))) float f32x4;
typedef __attribute__((ext_vector_type(8))) unsigned short u16x8;

// log2(e)/8 : folds the 1/sqrt(64) logit scale into exp2 (applied to Q in gemm1)
#define SC_LOG2E 0.18033688011112042f

#if __has_builtin(__builtin_amdgcn_exp2f)
#define EXP2F(x) __builtin_amdgcn_exp2f(x)
#else
#define EXP2F(x) __expf(0.6931471805599453f * (x))
#endif

__device__ __forceinline__ unsigned short f2bf(float f) {
    __hip_bfloat16 h = __float2bfloat16(f);
    return __builtin_bit_cast(unsigned short, h);
}
__device__ __forceinline__ float bf2f(unsigned short u) {
    union { unsigned int i; float f; } v;
    v.i = ((unsigned int)u) << 16;
    return v.f;
}
__device__ __forceinline__ unsigned int cvtpk_bf16(float lo, float hi) {
    unsigned int r;
    asm("v_cvt_pk_bf16_f32 %0, %1, %2" : "=v"(r) : "v"(lo), "v"(hi));
    return r;
}

__device__ __forceinline__ void gld_lds16(const void* g, void* s) {
    __builtin_amdgcn_global_load_lds(
        (__attribute__((address_space(1))) void*)(void*)g,
        (__attribute__((address_space(3))) void*)s, 16, 0, 0);
}

// ---------------------------------------------------------------------------
// fused fp32 -> bf16 cast for x, w_in, w_out (one launch)
// ---------------------------------------------------------------------------
#define NX4  (4096 * 1024 / 4)
#define NWI4 (3072 * 1024 / 4)
#define NWO4 (1024 * 1024 / 4)
__global__ void cast3_kernel(const float* __restrict__ x,
                             const float* __restrict__ wi,
                             const float* __restrict__ wo,
                             unsigned short* __restrict__ ox,
                             unsigned short* __restrict__ owi,
                             unsigned short* __restrict__ owo) {
    int i = blockIdx.x * blockDim.x + threadIdx.x;
    const float* s;
    unsigned short* d;
    int off;
    if (i < NX4)              { s = x;  d = ox;  off = i; }
    else if (i < NX4 + NWI4)  { s = wi; d = owi; off = i - NX4; }
    else                      { s = wo; d = owo; off = i - NX4 - NWI4; }
    float4 v = ((const float4*)s)[off];
    ushort4 u;
    u.x = f2bf(v.x); u.y = f2bf(v.y); u.z = f2bf(v.z); u.w = f2bf(v.w);
    ((ushort4*)d)[off] = u;
}

// ---------------------------------------------------------------------------
// GEMM: C[m,n] = sum_k A[m,k] * B[n,k]   (A:[M,K] bf16, B:[N,K] bf16)
// MODE 0 (QKV GEMM, N=3072): bn<8 -> Q, stored *SC_LOG2E; bn in [8,16) -> K,
//   stored plain bf16; bn in [16,24) -> V, NOT stored to qkv: instead the
//   64x64 per-wave tile is written TRANSPOSED to vtg[bh][d][k] (fused vtran)
//   and its column-sums go to ts[bh][t][d] (fused vsuf source).
//   Wave->(bh,t) mapping is bijective across the grid: h=(bn-16)*2+wc,
//   b=(row0+wr*64)>>11, t=((row0+wr*64)&2047)>>6 -> plain stores, no atomics.
// MODE 1 (out GEMM): f32 store to C.
// ---------------------------------------------------------------------------
template<int MODE>
__global__ __launch_bounds__(256, 3)
void gemm_bt(const unsigned short* __restrict__ A,
             const unsigned short* __restrict__ B,
             void* __restrict__ C, int M, int N, int K,
             unsigned short* __restrict__ vtg,
             float* __restrict__ ts) {
    (void)M;
    __shared__ unsigned short As[128 * 32];
    __shared__ unsigned short Bs[128 * 32];
    const int tid = threadIdx.x;
    const int nb = N >> 7;
    const int bm = blockIdx.x / nb;
    const int bn = blockIdx.x % nb;
    const int w  = tid >> 6, l = tid & 63;
    const int wr = w >> 1,  wc = w & 1;
    const int lr = l & 15,  lg = l >> 4;

    f32x4 acc[4][4] = {};

    const unsigned short* Ab = A + (size_t)bm * 128 * K;
    const unsigned short* Bb = B + (size_t)bn * 128 * K;

    const int c0 = tid, c1 = tid + 256;
    const int ar0 = c0 >> 2, ak0 = (c0 & 3) * 8;
    const int ar1 = c1 >> 2, ak1 = (c1 & 3) * 8;

    for (int kt = 0; kt < K; kt += 32) {
        __syncthreads();
        gld_lds16(Ab + (size_t)ar0 * K + kt + ak0, As + c0 * 8);
        gld_lds16(Ab + (size_t)ar1 * K + kt + ak1, As + c1 * 8);
        gld_lds16(Bb + (size_t)ar0 * K + kt + ak0, Bs + c0 * 8);
        gld_lds16(Bb + (size_t)ar1 * K + kt + ak1, Bs + c1 * 8);
        __syncthreads();

        bf16x8 af[4], bfr[4];
#pragma unroll
        for (int i = 0; i < 4; i++)
            af[i] = *(const bf16x8*)(As + (wr * 64 + i * 16 + lr) * 32 + lg * 8);
#pragma unroll
        for (int i = 0; i < 4; i++)
            bfr[i] = *(const bf16x8*)(Bs + (wc * 64 + i * 16 + lr) * 32 + lg * 8);
#pragma unroll
        for (int mi = 0; mi < 4; mi++)
#pragma unroll
            for (int ni = 0; ni < 4; ni++)
                acc[mi][ni] = __builtin_amdgcn_mfma_f32_16x16x32_bf16(
                    af[mi], bfr[ni], acc[mi][ni], 0, 0, 0);
    }

    const int row0 = bm * 128 + wr * 64;
    const int col0 = bn * 128 + wc * 64;

    if (MODE == 0 && bn >= 16) {
        // ---- fused V transpose + column sums ----
        const int h     = (bn - 16) * 2 + wc;
        const int krow0 = row0;                 // wave's 64 token rows
        const int bb    = krow0 >> 11;
        const int kloc0 = krow0 & 2047;
        const int bh    = bb * 16 + h;
        const int t     = kloc0 >> 6;
#pragma unroll
        for (int ni = 0; ni < 4; ni++) {
            const size_t dbase = ((size_t)(bh * 64 + ni * 16 + lr)) * TSEQ;
#pragma unroll
            for (int mi = 0; mi < 4; mi++) {
                uint2 pk;
                pk.x = cvtpk_bf16(acc[mi][ni][0], acc[mi][ni][1]);
                pk.y = cvtpk_bf16(acc[mi][ni][2], acc[mi][ni][3]);
                *(uint2*)(vtg + dbase + kloc0 + mi * 16 + lg * 4) = pk;
            }
        }
#pragma unroll
        for (int ni = 0; ni < 4; ni++) {
            float sum = 0.f;
#pragma unroll
            for (int mi = 0; mi < 4; mi++)
#pragma unroll
                for (int r = 0; r < 4; r++) sum += acc[mi][ni][r];
            sum += __shfl_xor(sum, 16);
            sum += __shfl_xor(sum, 32);
            if (lg == 0)
                ts[((size_t)bh * 32 + t) * 64 + ni * 16 + lr] = sum;
        }
        return;
    }

    const float qsc = (MODE == 0 && bn < 8) ? SC_LOG2E : 1.0f;
#pragma unroll
    for (int mi = 0; mi < 4; mi++)
#pragma unroll
        for (int ni = 0; ni < 4; ni++)
#pragma unroll
            for (int r = 0; r < 4; r++) {
                const int row = row0 + mi * 16 + lg * 4 + r;
                const int col = col0 + ni * 16 + lr;
                if (MODE == 1)
                    ((float*)C)[(size_t)row * N + col] = acc[mi][ni][r];
                else
                    ((unsigned short*)C)[(size_t)row * N + col] =
                        f2bf(acc[mi][ni][r] * qsc);
            }
}

// ---------------------------------------------------------------------------
// Attention v10 (R10-verified): consecutive strip pairs, 4-wave blocks,
// dbuf LDS K/V^T, plain __syncthreads, SWAPPED QK^T:
//   S^T = mfma(K, Q): lane (lg,lr) holds S^T[k=f*16+lg*4+r][q=lr]
// -> P packed via v_cvt_pk_bf16_f32 + b64 writes; LDS P layout unchanged.
// -> rsum lane-local + 2 shfl_xor at end.
// vsuf folded in epilogue: sums ts[bh][t>strip] directly (L2-hot).
// ---------------------------------------------------------------------------
__global__ __launch_bounds__(256, 2)
void attn_kernel(const unsigned short* __restrict__ qkv,
                 const unsigned short* __restrict__ vtg,
                 const float* __restrict__ ts,
                 unsigned short* __restrict__ out) {
    __shared__ __attribute__((aligned(16))) unsigned short Ks[2][4096];
    __shared__ __attribute__((aligned(16))) unsigned short Vs[2][4096];
    __shared__ __attribute__((aligned(16))) unsigned short Pl[4][32 * 72];

    const int tid = threadIdx.x;
    const int w = tid >> 6, l = tid & 63, lr = l & 15, lg = l >> 4;
    const int bid = blockIdx.x;
    const int j  = bid >> 5;
    const int s  = (j < 8) ? j : 23 - j;             // strip pair (2s, 2s+1)
    const int bh = (bid & 7) * 4 + ((bid >> 3) & 3); // XCD-pinned (b,h)
    const int b = bh >> 4, h = bh & 15;
    const int strip  = 2 * s + ((w < 2) ? 1 : 0);    // this wave's 64-row strip
    const int lastkt = strip;                        // wave's diagonal k-tile
    const int ntiles = 2 * s + 2;                    // staged tiles
    const size_t rowbase = (size_t)b * TSEQ;
    const int qrow0 = strip * 64 + (w & 1) * 32;

    // Q fragments, pre-scaled by SC_LOG2E in gemm1
    bf16x8 qf[2][2];
#pragma unroll
    for (int mi = 0; mi < 2; mi++) {
        const unsigned short* qp =
            qkv + (rowbase + qrow0 + mi * 16 + lr) * 3072 + h * 64 + lg * 8;
        qf[mi][0] = *(const bf16x8*)qp;
        qf[mi][1] = *(const bf16x8*)(qp + 32);
    }

    // staging source pointers, fragment order
    const unsigned short* ksrc[2];
    const unsigned short* vsrc[2];
#pragma unroll
    for (int jj = 0; jj < 2; jj++) {
        const int d = tid + jj * 256;
        const int fr = (d >> 7) * 16 + (d & 15);
        const int cc = ((d >> 6) & 1) * 32 + ((d & 63) >> 4) * 8;
        ksrc[jj] = qkv + (rowbase + fr) * 3072 + 1024 + h * 64 + cc;
        vsrc[jj] = vtg + ((size_t)bh * 64 + fr) * TSEQ + cc;
    }

#define STAGE(kt_, bufi) do {                                      \
        const size_t ko_ = (size_t)(kt_) * 64 * 3072;              \
        const int vo_ = (kt_) * 64;                                \
        gld_lds16(ksrc[0] + ko_, &Ks[bufi][tid * 8]);              \
        gld_lds16(ksrc[1] + ko_, &Ks[bufi][tid * 8 + 2048]);       \
        gld_lds16(vsrc[0] + vo_, &Vs[bufi][tid * 8]);              \
        gld_lds16(vsrc[1] + vo_, &Vs[bufi][tid * 8 + 2048]);       \
    } while (0)

    f32x4 o[2][4] = {};
    float ps[2] = {0.f, 0.f};     // lane-local rsum partial for q = (mi, lr)
    unsigned short* pw = &Pl[w][0];

    STAGE(0, 0);
    __syncthreads();

    int cur = 0;
    for (int kt = 0; kt < ntiles; ++kt) {
        if (kt + 1 < ntiles) STAGE(kt + 1, cur ^ 1);

        if (kt <= lastkt) {   // wave-uniform: skip tiles past this strip's diag
            const unsigned short* kc = Ks[cur];
            const unsigned short* vc = Vs[cur];

            bf16x8 kb[4][2];
#pragma unroll
            for (int f = 0; f < 4; f++) {
                kb[f][0] = *(const bf16x8*)(kc + ((f * 2 + 0) * 64 + l) * 8);
                kb[f][1] = *(const bf16x8*)(kc + ((f * 2 + 1) * 64 + l) * 8);
            }

            // S^T = K Q^T (swapped operands): lane holds q=lr, k=f*16+lg*4+r
            float pvv[2][4][4];
            __builtin_amdgcn_s_setprio(1);
#pragma unroll
            for (int mi = 0; mi < 2; mi++)
#pragma unroll
                for (int f = 0; f < 4; f++) {
                    f32x4 z = {0.f, 0.f, 0.f, 0.f};
                    f32x4 sv = __builtin_amdgcn_mfma_f32_16x16x32_bf16(kb[f][0], qf[mi][0], z, 0, 0, 0);
                    sv = __builtin_amdgcn_mfma_f32_16x16x32_bf16(kb[f][1], qf[mi][1], sv, 0, 0, 0);
#pragma unroll
                    for (int r = 0; r < 4; r++) pvv[mi][f][r] = sv[r];
                }
            __builtin_amdgcn_s_setprio(0);

            if (kt == lastkt) {  // diagonal tile only: tril zeroing (exp2(0)=1)
#pragma unroll
                for (int mi = 0; mi < 2; mi++) {
                    const int qr = qrow0 + mi * 16 + lr;
#pragma unroll
                    for (int f = 0; f < 4; f++)
#pragma unroll
                        for (int r = 0; r < 4; r++) {
                            const int kcol = kt * 64 + f * 16 + lg * 4 + r;
                            if (kcol > qr) pvv[mi][f][r] = 0.f;
                        }
                }
            }

            // exp2 + lane-local rsum + cvt_pk + b64 pack to P tile
#pragma unroll
            for (int mi = 0; mi < 2; mi++)
#pragma unroll
                for (int f = 0; f < 4; f++) {
                    float p0 = EXP2F(pvv[mi][f][0]);
                    float p1 = EXP2F(pvv[mi][f][1]);
                    float p2 = EXP2F(pvv[mi][f][2]);
                    float p3 = EXP2F(pvv[mi][f][3]);
                    ps[mi] += (p0 + p1) + (p2 + p3);
                    uint2 pk;
                    pk.x = cvtpk_bf16(p0, p1);
                    pk.y = cvtpk_bf16(p2, p3);
                    *(uint2*)(pw + (mi * 16 + lr) * 72 + f * 16 + lg * 4) = pk;
                }

            bf16x8 pa[2][2];
#pragma unroll
            for (int mi = 0; mi < 2; mi++) {
                pa[mi][0] = *(const bf16x8*)(pw + (mi * 16 + lr) * 72 + lg * 8);
                pa[mi][1] = *(const bf16x8*)(pw + (mi * 16 + lr) * 72 + 32 + lg * 8);
            }
            bf16x8 vb[4][2];
#pragma unroll
            for (int f2 = 0; f2 < 4; f2++) {
                vb[f2][0] = *(const bf16x8*)(vc + ((f2 * 2 + 0) * 64 + l) * 8);
                vb[f2][1] = *(const bf16x8*)(vc + ((f2 * 2 + 1) * 64 + l) * 8);
            }
            __builtin_amdgcn_s_setprio(1);
#pragma unroll
            for (int mi = 0; mi < 2; mi++)
#pragma unroll
                for (int f2 = 0; f2 < 4; f2++) {
                    o[mi][f2] = __builtin_amdgcn_mfma_f32_16x16x32_bf16(pa[mi][0], vb[f2][0], o[mi][f2], 0, 0, 0);
                    o[mi][f2] = __builtin_amdgcn_mfma_f32_16x16x32_bf16(pa[mi][1], vb[f2][1], o[mi][f2], 0, 0, 0);
                }
            __builtin_amdgcn_s_setprio(0);
        }

        __syncthreads();
        cur ^= 1;
    }
#undef STAGE

    // rsum finalize: reduce across lg groups (lanes sharing lr)
#pragma unroll
    for (int mi = 0; mi < 2; mi++) {
        ps[mi] += __shfl_xor(ps[mi], 16);
        ps[mi] += __shfl_xor(ps[mi], 32);
    }
    // redistribute to o-row owners: row q = qrow0 + mi*16 + lg*4 + r
    float rget[2][4];
#pragma unroll
    for (int mi = 0; mi < 2; mi++)
#pragma unroll
        for (int r = 0; r < 4; r++)
            rget[mi][r] = __shfl(ps[mi], lg * 4 + r);

    // future-tile V column sums (vsuf folded in): tpv[f2] = sum_{t>strip}
    float tpv[4] = {0.f, 0.f, 0.f, 0.f};
    for (int t = lastkt + 1; t < 32; ++t) {
        const float* tsp = ts + ((size_t)bh * 32 + t) * 64 + lr;
#pragma unroll
        for (int f2 = 0; f2 < 4; f2++) tpv[f2] += tsp[f2 * 16];
    }

    // epilogue: closed-form future part, normalize, store
    const float nmask = (float)((31 - lastkt) * 64);
#pragma unroll
    for (int mi = 0; mi < 2; mi++)
#pragma unroll
        for (int r = 0; r < 4; r++) {
            const float inv = 1.f / (rget[mi][r] + nmask);
#pragma unroll
            for (int f2 = 0; f2 < 4; f2++) {
                float num = o[mi][f2][r] + tpv[f2];
                out[(rowbase + qrow0 + mi * 16 + lg * 4 + r) * 1024 + h * 64 + f2 * 16 + lr] =
                    f2bf(num * inv);
            }
        }
}

// ---------------------------------------------------------------------------
extern "C" void kernel_launch(void* const* d_in, const int* in_sizes, int n_in,
                              void* d_out, int out_size, void* d_ws, size_t ws_size,
                              hipStream_t stream) {
    const float* x     = (const float*)d_in[0];
    const float* w_in  = (const float*)d_in[1];
    const float* w_out = (const float*)d_in[2];

    unsigned short* ws  = (unsigned short*)d_ws;
    unsigned short* xb  = ws;                            // 4096*1024
    unsigned short* wib = xb  + (size_t)4096 * 1024;     // 3072*1024
    unsigned short* wob = wib + (size_t)3072 * 1024;     // 1024*1024
    unsigned short* qkv = wob + (size_t)1024 * 1024;     // 4096*3072
    unsigned short* ao  = qkv + (size_t)4096 * 3072;     // 4096*1024
    float* tsbuf = (float*)(ao + (size_t)4096 * 1024);   // 32*32*64 f32
    unsigned short* vtg = (unsigned short*)(tsbuf + 32 * 32 * 64); // 32*64*2048

    cast3_kernel<<<(NX4 + NWI4 + NWO4) / 256, 256, 0, stream>>>(
        x, w_in, w_out, xb, wib, wob);

    // gemm1: QKV + fused V-transpose (vtg) + fused V tile colsums (tsbuf)
    gemm_bt<0><<<(4096 / 128) * (3072 / 128), 256, 0, stream>>>(
        xb, wib, qkv, 4096, 3072, 1024, vtg, tsbuf);
    attn_kernel<<<512, 256, 0, stream>>>(qkv, vtg, tsbuf, ao);
    gemm_bt<1><<<(4096 / 128) * (1024 / 128), 256, 0, stream>>>(
        ao, wob, (float*)d_out, 4096, 1024, 1024, nullptr, nullptr);
}